// Round 1
// baseline (561.175 us; speedup 1.0000x reference)
//
#include <hip/hip_runtime.h>
#include <stdint.h>

#define AS1 __attribute__((address_space(1)))
#define AS3 __attribute__((address_space(3)))

typedef __attribute__((ext_vector_type(4))) float f32x4;
typedef __attribute__((ext_vector_type(8))) short s16x8;

static constexpr int NTOK = 16384;
static constexpr int H    = 1024;
static constexpr int F    = 2048;
static constexpr int TWOF = 4096;
static constexpr int NEXP = 8;
static constexpr int MP   = NTOK + NEXP * 128;  // 17408 padded rows
static constexpr int MAXT = NTOK / 128 + NEXP;  // 136 worst-case row tiles

// meta int layout: [0..7] cnt, [8..15] cursor, [16..24] prow, [32..40] toff,
// [48] total_tiles, [64..] tile_expert, [256..] tile_row0
__device__ __forceinline__ ushort f2bf(float f) {
  union { float fv; uint32_t u; } v; v.fv = f;
  return (ushort)((v.u + 0x7FFFu + ((v.u >> 16) & 1u)) >> 16);
}

__device__ __forceinline__ void gload_lds16(const void* g, void* l) {
  __builtin_amdgcn_global_load_lds((const AS1 uint32_t*)g, (AS3 uint32_t*)l, 16, 0, 0);
}

__global__ void k_hist(const int* __restrict__ eid, int* __restrict__ meta) {
  int i = blockIdx.x * blockDim.x + threadIdx.x;
  if (i < NTOK) atomicAdd(&meta[eid[i]], 1);
}

__global__ void k_scan(int* __restrict__ meta) {
  if (threadIdx.x != 0) return;
  int prow = 0, toff = 0;
  meta[16] = 0; meta[32] = 0;
  for (int e = 0; e < NEXP; ++e) {
    int c = meta[e];
    int t = (c + 127) >> 7;
    toff += t; prow += t << 7;
    meta[16 + e + 1] = prow;
    meta[32 + e + 1] = toff;
  }
  meta[48] = toff;
  int e = 0;
  for (int t = 0; t < toff; ++t) {
    while (t >= meta[32 + e + 1]) ++e;
    meta[64 + t]  = e;
    meta[256 + t] = meta[16 + e] + ((t - meta[32 + e]) << 7);
  }
}

__global__ void k_scatter(const int* __restrict__ eid, int* __restrict__ meta,
                          int* __restrict__ sidx) {
  int i = blockIdx.x * blockDim.x + threadIdx.x;
  if (i < NTOK) {
    int e = eid[i];
    int pos = meta[16 + e] + atomicAdd(&meta[8 + e], 1);
    sidx[pos] = i;
  }
}

// gather tokens (fp32) into padded sorted order as bf16 [MP][H]
__global__ void k_gather(const float* __restrict__ tok, const int* __restrict__ sidx,
                         ushort* __restrict__ A) {
  int t = blockIdx.x * blockDim.x + threadIdx.x;
  long flat = (long)t * 8;
  int row = (int)(flat >> 10), col = (int)(flat & 1023);
  if (row >= MP) return;
  int idx = sidx[row];
  s16x8 o = (s16x8)0;
  if (idx >= 0) {
    const f32x4* p = (const f32x4*)(tok + (size_t)idx * H + col);
    f32x4 a = p[0], b = p[1];
    o[0] = (short)f2bf(a.x); o[1] = (short)f2bf(a.y);
    o[2] = (short)f2bf(a.z); o[3] = (short)f2bf(a.w);
    o[4] = (short)f2bf(b.x); o[5] = (short)f2bf(b.y);
    o[6] = (short)f2bf(b.z); o[7] = (short)f2bf(b.w);
  }
  *(s16x8*)(A + flat) = o;
}

// transpose+convert: src [Z][K][N] fp32 -> dst [Z][N][K] bf16, 64x64 tiles
__global__ void k_transpose(const float* __restrict__ src, ushort* __restrict__ dst,
                            int K, int N) {
  __shared__ __align__(16) ushort t[64 * 80];
  int nt = blockIdx.x, kt = blockIdx.y, z = blockIdx.z;
  const float* s = src + (size_t)z * K * N + (size_t)(kt * 64) * N + nt * 64;
  ushort* d = dst + (size_t)z * N * K + (size_t)(nt * 64) * K + kt * 64;
  int tid = threadIdx.x;
#pragma unroll
  for (int r = 0; r < 4; ++r) {
    int i = r * 1024 + tid * 4;
    int kl = i >> 6, nl = i & 63;
    f32x4 v = *(const f32x4*)(s + (size_t)kl * N + nl);
    t[(nl + 0) * 80 + kl] = f2bf(v.x);
    t[(nl + 1) * 80 + kl] = f2bf(v.y);
    t[(nl + 2) * 80 + kl] = f2bf(v.z);
    t[(nl + 3) * 80 + kl] = f2bf(v.w);
  }
  __syncthreads();
#pragma unroll
  for (int r = 0; r < 2; ++r) {
    int i = r * 2048 + tid * 8;
    int nl = i >> 6, k8 = i & 63;
    s16x8 v = *(const s16x8*)&t[nl * 80 + k8];
    *(s16x8*)(d + (size_t)nl * K + k8) = v;
  }
}

// GEMM1: A[MP][H] bf16 (padded-sorted tokens) x Wgu^T [E][4096][1024] bf16
// block: 128 rows x 64 hidden cols (gate col c & up col F+c), fused SwiGLU -> Hid bf16 [MP][F]
__global__ __launch_bounds__(256)
void k_gemm1(const ushort* __restrict__ A, const ushort* __restrict__ Wt,
             ushort* __restrict__ Hid, const int* __restrict__ meta) {
  int t = blockIdx.x;
  if (t >= meta[48]) return;
  int ct = blockIdx.y;  // 0..31
  int e = meta[64 + t], row0 = meta[256 + t];
  __shared__ __align__(16) ushort sA[128 * 64];
  __shared__ __align__(16) ushort sG[64 * 64];
  __shared__ __align__(16) ushort sU[64 * 64];
  const int tid = threadIdx.x, lane = tid & 63, wid = tid >> 6;
  const int wm = wid >> 1, wn = wid & 1;
  const ushort* Abase = A + (size_t)row0 * H;
  const ushort* Gbase = Wt + (size_t)e * TWOF * H + (size_t)(ct * 64) * H;
  const ushort* Ubase = Wt + (size_t)e * TWOF * H + (size_t)(F + ct * 64) * H;

  f32x4 accg[4][2] = {}; f32x4 accu[4][2] = {};

  for (int kt = 0; kt < H / 64; ++kt) {
    int kk = kt * 64;
#pragma unroll
    for (int is = 0; is < 4; ++is) {
      int L = is * 4096 + wid * 1024 + (lane << 4);
      int row = L >> 7, blk = (L >> 4) & 7;
      gload_lds16(Abase + (size_t)row * H + kk + ((blk ^ (row & 7)) << 3),
                  (void*)(sA + ((is * 4096 + wid * 1024) >> 1)));
    }
#pragma unroll
    for (int is = 0; is < 2; ++is) {
      int L = is * 4096 + wid * 1024 + (lane << 4);
      int row = L >> 7, blk = (L >> 4) & 7;
      int so = (blk ^ (row & 7)) << 3;
      gload_lds16(Gbase + (size_t)row * H + kk + so,
                  (void*)(sG + ((is * 4096 + wid * 1024) >> 1)));
      gload_lds16(Ubase + (size_t)row * H + kk + so,
                  (void*)(sU + ((is * 4096 + wid * 1024) >> 1)));
    }
    __syncthreads();
#pragma unroll
    for (int ks = 0; ks < 2; ++ks) {
      const int l15 = lane & 15, g = lane >> 4;
      s16x8 af[4], gf[2], uf[2];
#pragma unroll
      for (int mf = 0; mf < 4; ++mf) {
        int row = wm * 64 + mf * 16 + l15;
        int blk = (ks * 4 + g) ^ (row & 7);
        af[mf] = *(const s16x8*)(sA + row * 64 + blk * 8);
      }
#pragma unroll
      for (int nf = 0; nf < 2; ++nf) {
        int row = wn * 32 + nf * 16 + l15;
        int blk = (ks * 4 + g) ^ (row & 7);
        gf[nf] = *(const s16x8*)(sG + row * 64 + blk * 8);
        uf[nf] = *(const s16x8*)(sU + row * 64 + blk * 8);
      }
#pragma unroll
      for (int mf = 0; mf < 4; ++mf)
#pragma unroll
        for (int nf = 0; nf < 2; ++nf) {
          accg[mf][nf] = __builtin_amdgcn_mfma_f32_16x16x32_bf16(af[mf], gf[nf], accg[mf][nf], 0, 0, 0);
          accu[mf][nf] = __builtin_amdgcn_mfma_f32_16x16x32_bf16(af[mf], uf[nf], accu[mf][nf], 0, 0, 0);
        }
    }
    __syncthreads();
  }
  const int l15 = lane & 15, g4 = (lane >> 4) * 4;
#pragma unroll
  for (int mf = 0; mf < 4; ++mf)
#pragma unroll
    for (int nf = 0; nf < 2; ++nf)
#pragma unroll
      for (int j = 0; j < 4; ++j) {
        int row = row0 + wm * 64 + mf * 16 + g4 + j;
        int col = ct * 64 + wn * 32 + nf * 16 + l15;
        float gv = accg[mf][nf][j], uv = accu[mf][nf][j];
        float h = gv / (1.0f + __expf(-gv)) * uv;
        Hid[(size_t)row * F + col] = f2bf(h);
      }
}

// GEMM2: Hid[MP][F] bf16 x Wdn^T [E][1024][2048] bf16 -> scatter fp32 out [NTOK][H]
__global__ __launch_bounds__(256)
void k_gemm2(const ushort* __restrict__ Hid, const ushort* __restrict__ Wt,
             float* __restrict__ Out, const int* __restrict__ meta,
             const int* __restrict__ sidx) {
  int t = blockIdx.x;
  if (t >= meta[48]) return;
  int ct = blockIdx.y;  // 0..7
  int e = meta[64 + t], row0 = meta[256 + t];
  __shared__ __align__(16) ushort sA[128 * 64];
  __shared__ __align__(16) ushort sB[128 * 64];
  const int tid = threadIdx.x, lane = tid & 63, wid = tid >> 6;
  const int wm = wid >> 1, wn = wid & 1;
  const ushort* Abase = Hid + (size_t)row0 * F;
  const ushort* Bbase = Wt + (size_t)e * H * F + (size_t)(ct * 128) * F;
  f32x4 acc[4][4] = {};
  for (int kt = 0; kt < F / 64; ++kt) {
    int kk = kt * 64;
#pragma unroll
    for (int is = 0; is < 4; ++is) {
      int L = is * 4096 + wid * 1024 + (lane << 4);
      int row = L >> 7, blk = (L >> 4) & 7;
      int so = (blk ^ (row & 7)) << 3;
      gload_lds16(Abase + (size_t)row * F + kk + so,
                  (void*)(sA + ((is * 4096 + wid * 1024) >> 1)));
      gload_lds16(Bbase + (size_t)row * F + kk + so,
                  (void*)(sB + ((is * 4096 + wid * 1024) >> 1)));
    }
    __syncthreads();
#pragma unroll
    for (int ks = 0; ks < 2; ++ks) {
      const int l15 = lane & 15, g = lane >> 4;
      s16x8 af[4], bfr[4];
#pragma unroll
      for (int mf = 0; mf < 4; ++mf) {
        int row = wm * 64 + mf * 16 + l15;
        int blk = (ks * 4 + g) ^ (row & 7);
        af[mf] = *(const s16x8*)(sA + row * 64 + blk * 8);
      }
#pragma unroll
      for (int nf = 0; nf < 4; ++nf) {
        int row = wn * 64 + nf * 16 + l15;
        int blk = (ks * 4 + g) ^ (row & 7);
        bfr[nf] = *(const s16x8*)(sB + row * 64 + blk * 8);
      }
#pragma unroll
      for (int mf = 0; mf < 4; ++mf)
#pragma unroll
        for (int nf = 0; nf < 4; ++nf)
          acc[mf][nf] = __builtin_amdgcn_mfma_f32_16x16x32_bf16(af[mf], bfr[nf], acc[mf][nf], 0, 0, 0);
    }
    __syncthreads();
  }
  const int l15 = lane & 15, g4 = (lane >> 4) * 4;
#pragma unroll
  for (int mf = 0; mf < 4; ++mf)
#pragma unroll
    for (int j = 0; j < 4; ++j) {
      int prow = row0 + wm * 64 + mf * 16 + g4 + j;
      int orig = sidx[prow];
      if (orig >= 0) {
#pragma unroll
        for (int nf = 0; nf < 4; ++nf) {
          int col = ct * 128 + wn * 64 + nf * 16 + l15;
          Out[(size_t)orig * H + col] = acc[mf][nf][j];
        }
      }
    }
}

extern "C" void kernel_launch(void* const* d_in, const int* in_sizes, int n_in,
                              void* d_out, int out_size, void* d_ws, size_t ws_size,
                              hipStream_t stream) {
  (void)in_sizes; (void)n_in; (void)out_size; (void)ws_size;
  const float* tokens = (const float*)d_in[0];
  const float* wgu    = (const float*)d_in[1];
  const float* wdn    = (const float*)d_in[2];
  const int*   eid    = (const int*)d_in[3];

  char* ws = (char*)d_ws;
  int*    meta  = (int*)ws;                                  // 8 KB
  int*    sidx  = (int*)(ws + 8192);                         // 17408 ints
  ushort* Abf   = (ushort*)(ws + 131072);                    // 35,651,584 B
  ushort* Hid   = (ushort*)(ws + 131072 + 35651584);         // 71,303,168 B
  ushort* Wgu_t = (ushort*)(ws + 131072 + 35651584 + 71303168);  // 67,108,864 B
  ushort* Wdn_t = Wgu_t;  // aliased: written after GEMM1 consumes Wgu_t

  hipMemsetAsync(meta, 0, 256, stream);
  hipMemsetAsync(sidx, 0xFF, MP * sizeof(int), stream);

  k_hist   <<<NTOK / 256, 256, 0, stream>>>(eid, meta);
  k_scan   <<<1, 1, 0, stream>>>(meta);
  k_scatter<<<NTOK / 256, 256, 0, stream>>>(eid, meta, sidx);
  k_gather <<<MP * H / 8 / 256, 256, 0, stream>>>(tokens, sidx, Abf);
  k_transpose<<<dim3(TWOF / 64, H / 64, NEXP), 256, 0, stream>>>(wgu, Wgu_t, H, TWOF);
  k_gemm1  <<<dim3(MAXT, F / 64), 256, 0, stream>>>(Abf, Wgu_t, Hid, meta);
  k_transpose<<<dim3(H / 64, F / 64, NEXP), 256, 0, stream>>>(wdn, Wdn_t, F, H);
  k_gemm2  <<<dim3(MAXT, H / 128), 256, 0, stream>>>(Hid, Wdn_t, (float*)d_out, meta, sidx);
}

// Round 2
// 494.847 us; speedup vs baseline: 1.1340x; 1.1340x over previous
//
#include <hip/hip_runtime.h>
#include <stdint.h>

#define AS1 __attribute__((address_space(1)))
#define AS3 __attribute__((address_space(3)))

typedef __attribute__((ext_vector_type(4))) float f32x4;
typedef __attribute__((ext_vector_type(8))) short s16x8;

static constexpr int NTOK = 16384;
static constexpr int H    = 1024;
static constexpr int F    = 2048;
static constexpr int TWOF = 4096;
static constexpr int NEXP = 8;
static constexpr int MP2  = NTOK + NEXP * 256;   // 18432 padded rows (256-aligned per expert)
static constexpr int MAXT256 = NTOK / 256 + NEXP;  // 72
static constexpr int MAXT128 = 2 * MAXT256;        // 144

// meta: [0..7] cnt, [8..15] cursor, [16..24] expert row start, [48] n256, [49] n128,
// [64..) t256 expert, [256..) t256 row0, [512..) t128 expert, [768..) t128 row0
__device__ __forceinline__ ushort f2bf(float f) {
  union { float fv; uint32_t u; } v; v.fv = f;
  return (ushort)((v.u + 0x7FFFu + ((v.u >> 16) & 1u)) >> 16);
}

__device__ __forceinline__ void gload_lds16(const void* g, void* l) {
  __builtin_amdgcn_global_load_lds((const AS1 uint32_t*)g, (AS3 uint32_t*)l, 16, 0, 0);
}

#define BAR() do { asm volatile("" ::: "memory"); __builtin_amdgcn_s_barrier(); asm volatile("" ::: "memory"); } while (0)
#define VM4() asm volatile("s_waitcnt vmcnt(4)" ::: "memory")
#define VM0() asm volatile("s_waitcnt vmcnt(0)" ::: "memory")

__global__ void k_hist(const int* __restrict__ eid, int* __restrict__ meta) {
  int i = blockIdx.x * blockDim.x + threadIdx.x;
  if (i < NTOK) atomicAdd(&meta[eid[i]], 1);
}

__global__ void k_scan(int* __restrict__ meta) {
  if (threadIdx.x != 0) return;
  int prow = 0, n256 = 0, n128 = 0;
  meta[16] = 0;
  for (int e = 0; e < NEXP; ++e) {
    int c = meta[e];
    int nt = (c + 255) >> 8;
    for (int k = 0; k < nt; ++k) {
      meta[64 + n256] = e;  meta[256 + n256] = prow;  ++n256;
      meta[512 + n128] = e; meta[768 + n128] = prow;        ++n128;
      meta[512 + n128] = e; meta[768 + n128] = prow + 128;  ++n128;
      prow += 256;
    }
    meta[16 + e + 1] = prow;
  }
  meta[48] = n256; meta[49] = n128;
}

__global__ void k_scatter(const int* __restrict__ eid, int* __restrict__ meta,
                          int* __restrict__ sidx) {
  int i = blockIdx.x * blockDim.x + threadIdx.x;
  if (i < NTOK) {
    int e = eid[i];
    int pos = meta[16 + e] + atomicAdd(&meta[8 + e], 1);
    sidx[pos] = i;
  }
}

__global__ void k_gather(const float* __restrict__ tok, const int* __restrict__ sidx,
                         ushort* __restrict__ A) {
  int t = blockIdx.x * blockDim.x + threadIdx.x;
  long flat = (long)t * 8;
  int row = (int)(flat >> 10), col = (int)(flat & 1023);
  if (row >= MP2) return;
  int idx = sidx[row];
  s16x8 o = (s16x8)0;
  if (idx >= 0) {
    const f32x4* p = (const f32x4*)(tok + (size_t)idx * H + col);
    f32x4 a = p[0], b = p[1];
    o[0] = (short)f2bf(a.x); o[1] = (short)f2bf(a.y);
    o[2] = (short)f2bf(a.z); o[3] = (short)f2bf(a.w);
    o[4] = (short)f2bf(b.x); o[5] = (short)f2bf(b.y);
    o[6] = (short)f2bf(b.z); o[7] = (short)f2bf(b.w);
  }
  *(s16x8*)(A + flat) = o;
}

// transpose+convert: src [Z][K][N] fp32 -> dst [Z][N][K] bf16, 64x64 tiles
__global__ void k_transpose(const float* __restrict__ src, ushort* __restrict__ dst,
                            int K, int N) {
  __shared__ __align__(16) ushort t[64 * 80];
  int nt = blockIdx.x, kt = blockIdx.y, z = blockIdx.z;
  const float* s = src + (size_t)z * K * N + (size_t)(kt * 64) * N + nt * 64;
  ushort* d = dst + (size_t)z * N * K + (size_t)(nt * 64) * K + kt * 64;
  int tid = threadIdx.x;
#pragma unroll
  for (int r = 0; r < 4; ++r) {
    int i = r * 1024 + tid * 4;
    int kl = i >> 6, nl = i & 63;
    f32x4 v = *(const f32x4*)(s + (size_t)kl * N + nl);
    t[(nl + 0) * 80 + kl] = f2bf(v.x);
    t[(nl + 1) * 80 + kl] = f2bf(v.y);
    t[(nl + 2) * 80 + kl] = f2bf(v.z);
    t[(nl + 3) * 80 + kl] = f2bf(v.w);
  }
  __syncthreads();
#pragma unroll
  for (int r = 0; r < 2; ++r) {
    int i = r * 2048 + tid * 8;
    int nl = i >> 6, k8 = i & 63;
    s16x8 v = *(const s16x8*)&t[nl * 80 + k8];
    *(s16x8*)(d + (size_t)nl * K + k8) = v;
  }
}

// ---------------- GEMM1: 256-row x 128-hidden-col tile, 8-phase schedule ----------------
// A[MP2][H] bf16 x Wgu^T [E][4096][1024] bf16 -> SwiGLU -> Hid bf16 [MP2][F]
// B LDS tile rows (256): for wave strip wn: [wn*64 .. wn*64+32) = gate cols ct*128+wn*32..+32,
//                                      [wn*64+32 .. +64) = up cols of the SAME hidden cols.
__global__ __launch_bounds__(512, 2)
void k_gemm1(const ushort* __restrict__ A, const ushort* __restrict__ Wt,
             ushort* __restrict__ Hid, const int* __restrict__ meta) {
  int lin = blockIdx.x;
  int swz = (lin & 7) * (MAXT256 * 16 / 8) + (lin >> 3);
  int t = swz >> 4, ct = swz & 15;
  if (t >= meta[48]) return;
  int e = meta[64 + t], row0 = meta[256 + t];

  extern __shared__ __align__(16) char smem[];
  ushort* sA0 = (ushort*)smem;             // [256][64]
  ushort* sA1 = (ushort*)(smem + 32768);
  ushort* sB0 = (ushort*)(smem + 65536);
  ushort* sB1 = (ushort*)(smem + 98304);

  const int tid = threadIdx.x, lane = tid & 63, wid = tid >> 6;
  const int wm = wid >> 2, wn = wid & 3;
  const int l15 = lane & 15, g = lane >> 4;

  // staging address precompute (swizzle blk^(row&7); (row&7)==((tid>>3)&7) for all halves)
  const int swzblk = (tid & 7) ^ ((tid >> 3) & 7);
  const ushort* aGbase = A + (size_t)(row0 + (tid >> 3)) * H + swzblk * 8;
  const int s63 = tid >> 3;            // 0..63 within a 64-row issue
  const int up = s63 >> 5;             // 0 gate, 1 up
  const int cc = s63 & 31;
  const ushort* bGbase = Wt + (size_t)e * TWOF * H
                       + (size_t)(up * F + ct * 128 + cc) * H + swzblk * 8;

  auto stageA = [&](ushort* dst, int h, int kt) {
    gload_lds16(aGbase + (size_t)(h * 128) * H + kt * 64,      dst + h * 8192 + wid * 512);
    gload_lds16(aGbase + (size_t)(h * 128 + 64) * H + kt * 64, dst + h * 8192 + 4096 + wid * 512);
  };
  auto stageB = [&](ushort* dst, int h, int kt) {
    gload_lds16(bGbase + (size_t)(h * 64) * H + kt * 64,       dst + h * 8192 + wid * 512);
    gload_lds16(bGbase + (size_t)(h * 64 + 32) * H + kt * 64,  dst + h * 8192 + 4096 + wid * 512);
  };

  f32x4 acc[8][4] = {};
  s16x8 bf[2][4];

  auto rdB = [&](const ushort* sBb) {
#pragma unroll
    for (int ks = 0; ks < 2; ++ks)
#pragma unroll
      for (int nf = 0; nf < 4; ++nf) {
        int r = wn * 64 + nf * 16 + l15;
        bf[ks][nf] = *(const s16x8*)(sBb + r * 64 + (((ks * 4 + g) ^ (l15 & 7)) << 3));
      }
  };

#define PHASE(sAb, Q, RDB_STMT, STAGE_STMT, VM_STMT) do {                         \
    RDB_STMT;                                                                     \
    s16x8 af[2][2];                                                               \
    _Pragma("unroll") for (int ks = 0; ks < 2; ++ks)                              \
      _Pragma("unroll") for (int mf = 0; mf < 2; ++mf) {                          \
        int r = wm * 128 + (Q) * 32 + mf * 16 + l15;                              \
        af[mf][ks] = *(const s16x8*)((sAb) + r * 64 + (((ks * 4 + g) ^ (l15 & 7)) << 3)); \
      }                                                                           \
    STAGE_STMT;                                                                   \
    BAR();                                                                        \
    __builtin_amdgcn_s_setprio(1);                                                \
    _Pragma("unroll") for (int ks = 0; ks < 2; ++ks)                              \
      _Pragma("unroll") for (int mf = 0; mf < 2; ++mf)                            \
        _Pragma("unroll") for (int nf = 0; nf < 4; ++nf)                          \
          acc[(Q) * 2 + mf][nf] = __builtin_amdgcn_mfma_f32_16x16x32_bf16(        \
              af[mf][ks], bf[ks][nf], acc[(Q) * 2 + mf][nf], 0, 0, 0);            \
    __builtin_amdgcn_s_setprio(0);                                                \
    VM_STMT;                                                                      \
    BAR();                                                                        \
  } while (0)

  constexpr int nkt = H / 64;     // 16
  constexpr int nit = nkt / 2;    // 8

  // prologue: A-buf0(K0), B-buf0(K0), B-buf1(K1); A-buf1(K1) staged in iter0 p1-p2
  stageA(sA0, 0, 0); stageA(sA0, 1, 0);
  stageB(sB0, 0, 0); stageB(sB0, 1, 0);
  stageB(sB1, 0, 1); stageB(sB1, 1, 1);
  VM4();
  BAR();

#pragma unroll
  for (int i = 0; i < nit; ++i) {
    const int T0 = 2 * i, T1 = 2 * i + 1;
    const bool more = (i < nit - 1);
    // phases 1-4: consume buf0 (K-tile T0)
    PHASE(sA0, 0, rdB(sB0), stageA(sA1, 0, T1), ((void)0));
    PHASE(sA0, 1, ((void)0), stageA(sA1, 1, T1), ((void)0));
    PHASE(sA0, 2, ((void)0), if (more) stageB(sB0, 0, T0 + 2), ((void)0));
    PHASE(sA0, 3, ((void)0), if (more) stageB(sB0, 1, T0 + 2), if (more) VM4(); else VM0());
    // phases 5-8: consume buf1 (K-tile T1)
    PHASE(sA1, 0, rdB(sB1), if (more) stageA(sA0, 0, T0 + 2), ((void)0));
    PHASE(sA1, 1, ((void)0), if (more) stageA(sA0, 1, T0 + 2), ((void)0));
    PHASE(sA1, 2, ((void)0), if (more) stageB(sB1, 0, T1 + 2), ((void)0));
    PHASE(sA1, 3, ((void)0), if (more) stageB(sB1, 1, T1 + 2), if (more) VM4(); else VM0());
  }
#undef PHASE

  // epilogue: SwiGLU in-lane (nf 0,1 = gate; nf 2,3 = up of same hidden cols)
  const int g4 = g * 4;
#pragma unroll
  for (int m = 0; m < 8; ++m)
#pragma unroll
    for (int nf = 0; nf < 2; ++nf)
#pragma unroll
      for (int j = 0; j < 4; ++j) {
        float gv = acc[m][nf][j], uv = acc[m][nf + 2][j];
        float h = gv / (1.0f + __expf(-gv)) * uv;
        int row = row0 + wm * 128 + m * 16 + g4 + j;
        int col = ct * 128 + wn * 32 + nf * 16 + l15;
        Hid[(size_t)row * F + col] = f2bf(h);
      }
}

// ---------------- GEMM2: 128x128 tile (round-1 structure) + tile128 meta + XCD swizzle ----
__global__ __launch_bounds__(256)
void k_gemm2(const ushort* __restrict__ Hid, const ushort* __restrict__ Wt,
             float* __restrict__ Out, const int* __restrict__ meta,
             const int* __restrict__ sidx) {
  int lin = blockIdx.x;
  int swz = (lin & 7) * (MAXT128 * 8 / 8) + (lin >> 3);
  int t = swz >> 3, ct = swz & 7;
  if (t >= meta[49]) return;
  int e = meta[512 + t], row0 = meta[768 + t];
  __shared__ __align__(16) ushort sA[128 * 64];
  __shared__ __align__(16) ushort sB[128 * 64];
  const int tid = threadIdx.x, lane = tid & 63, wid = tid >> 6;
  const int wm = wid >> 1, wn = wid & 1;
  const ushort* Abase = Hid + (size_t)row0 * F;
  const ushort* Bbase = Wt + (size_t)e * H * F + (size_t)(ct * 128) * F;
  f32x4 acc[4][4] = {};
  for (int kt = 0; kt < F / 64; ++kt) {
    int kk = kt * 64;
#pragma unroll
    for (int is = 0; is < 4; ++is) {
      int L = is * 4096 + wid * 1024 + (lane << 4);
      int row = L >> 7, blk = (L >> 4) & 7;
      int so = (blk ^ (row & 7)) << 3;
      gload_lds16(Abase + (size_t)row * F + kk + so,
                  (void*)(sA + ((is * 4096 + wid * 1024) >> 1)));
      gload_lds16(Bbase + (size_t)row * F + kk + so,
                  (void*)(sB + ((is * 4096 + wid * 1024) >> 1)));
    }
    __syncthreads();
#pragma unroll
    for (int ks = 0; ks < 2; ++ks) {
      const int l15 = lane & 15, g = lane >> 4;
      s16x8 af[4], bfr[4];
#pragma unroll
      for (int mf = 0; mf < 4; ++mf) {
        int row = wm * 64 + mf * 16 + l15;
        int blk = (ks * 4 + g) ^ (row & 7);
        af[mf] = *(const s16x8*)(sA + row * 64 + blk * 8);
      }
#pragma unroll
      for (int nf = 0; nf < 4; ++nf) {
        int row = wn * 64 + nf * 16 + l15;
        int blk = (ks * 4 + g) ^ (row & 7);
        bfr[nf] = *(const s16x8*)(sB + row * 64 + blk * 8);
      }
#pragma unroll
      for (int mf = 0; mf < 4; ++mf)
#pragma unroll
        for (int nf = 0; nf < 4; ++nf)
          acc[mf][nf] = __builtin_amdgcn_mfma_f32_16x16x32_bf16(af[mf], bfr[nf], acc[mf][nf], 0, 0, 0);
    }
    __syncthreads();
  }
  const int l15 = lane & 15, g4 = (lane >> 4) * 4;
#pragma unroll
  for (int mf = 0; mf < 4; ++mf)
#pragma unroll
    for (int j = 0; j < 4; ++j) {
      int prow = row0 + wm * 64 + mf * 16 + g4 + j;
      int orig = sidx[prow];
      if (orig >= 0) {
#pragma unroll
        for (int nf = 0; nf < 4; ++nf) {
          int col = ct * 128 + wn * 64 + nf * 16 + l15;
          Out[(size_t)orig * H + col] = acc[mf][nf][j];
        }
      }
    }
}

extern "C" void kernel_launch(void* const* d_in, const int* in_sizes, int n_in,
                              void* d_out, int out_size, void* d_ws, size_t ws_size,
                              hipStream_t stream) {
  (void)in_sizes; (void)n_in; (void)out_size; (void)ws_size;
  const float* tokens = (const float*)d_in[0];
  const float* wgu    = (const float*)d_in[1];
  const float* wdn    = (const float*)d_in[2];
  const int*   eid    = (const int*)d_in[3];

  char* ws = (char*)d_ws;
  int*    meta  = (int*)ws;                       // 8 KB
  int*    sidx  = (int*)(ws + 8192);              // 18432 ints
  ushort* Abf   = (ushort*)(ws + 131072);                         // 37,748,736 B
  ushort* Hid   = (ushort*)(ws + 131072 + 37748736);              // 75,497,472 B
  ushort* Wgu_t = (ushort*)(ws + 131072 + 37748736 + 75497472);   // 67,108,864 B
  ushort* Wdn_t = Wgu_t;  // aliased: written after GEMM1 consumes Wgu_t

  hipFuncSetAttribute((const void*)k_gemm1,
                      hipFuncAttributeMaxDynamicSharedMemorySize, 131072);

  hipMemsetAsync(meta, 0, 256, stream);
  hipMemsetAsync(sidx, 0xFF, MP2 * sizeof(int), stream);

  k_hist   <<<NTOK / 256, 256, 0, stream>>>(eid, meta);
  k_scan   <<<1, 1, 0, stream>>>(meta);
  k_scatter<<<NTOK / 256, 256, 0, stream>>>(eid, meta, sidx);
  k_gather <<<MP2 * H / 8 / 256, 256, 0, stream>>>(tokens, sidx, Abf);
  k_transpose<<<dim3(TWOF / 64, H / 64, NEXP), 256, 0, stream>>>(wgu, Wgu_t, H, TWOF);
  k_gemm1  <<<MAXT256 * 16, 512, 131072, stream>>>(Abf, Wgu_t, Hid, meta);
  k_transpose<<<dim3(H / 64, F / 64, NEXP), 256, 0, stream>>>(wdn, Wdn_t, F, H);
  k_gemm2  <<<MAXT128 * 8, 256, 0, stream>>>(Hid, Wdn_t, (float*)d_out, meta, sidx);
}